// Round 3
// baseline (2355.823 us; speedup 1.0000x reference)
//
#include <hip/hip_runtime.h>
#include <hip/hip_bf16.h>
#include <math.h>

// ---------------------------------------------------------------------------
// LSTM text classifier forward, MI355X/gfx950.  Round 3.
//
// R2 post-mortem: VGPR_Count=68 -> compiler sank the U-fragment loads into
// the t-loop AGAIN; each block re-read its 128KB U-slice from L2 every step
// (~1us/step), plus central-counter sync (2 serialized L3 RTs) and zlds
// bank conflicts (5M cycles).
//
// R3:
//  - U fragments pinned in VGPRs via opaque inline asm after the pre-loop
//    load: the value is defined by volatile asm -> cannot be rematerialized
//    in-loop. KEY CHECKPOINT: VGPR_Count must read ~190+, not ~70.
//  - 4 waves/block, wave owns ALL 4 gates of one 16-unit tile
//    (ureg[4][8] = 128 VGPR/wave). i/f/g/o land in the same wave's
//    accumulators -> no zlds gate exchange, 2 fewer barriers, no LDS
//    conflicts. c,h fully in-register.
//  - Sync: per-producer release flag; waves 1..3 spin on one sibling each
//    and pull its 2KB slice immediately (3 arrivals pipeline).
//
// Structure: 16 blocks = 4 batch-groups (16 batches) x 4 unit-slices
// (64 units). Exchange h (2KB bf16) among the 4 sibling blocks of a group
// via agent-scope atomics in L3; double-buffered data slots (t&1), flags
// unique per (t, block) -> no ABA; 16 blocks trivially co-resident.
//
// MFMA 16x16x32 bf16 layouts (m89/m91):
//   A[m][k]: m=lane&15, k=(lane>>4)*8+j      B[k][n]: n=lane&15, same k
//   C/D:     col=lane&15, row=(lane>>4)*4+reg
// ---------------------------------------------------------------------------

typedef __bf16 bf16_t;
typedef bf16_t bf16x8 __attribute__((ext_vector_type(8)));
typedef bf16_t bf16x4 __attribute__((ext_vector_type(4)));
typedef float  f32x4  __attribute__((ext_vector_type(4)));

#define T_SZ 512
#define HID 256
#define G4 1024
#define NCLS 20

// workspace layout (bytes)
#define WS_UPACK 0u
#define WS_WPACK (512u * 1024u)
#define WS_HFIN  (1024u * 1024u)                  // 64 KB
#define WS_FLAG  (1024u * 1024u + 64u * 1024u)    // 32 KB (512*16 uints)
#define WS_HEXCH (1024u * 1024u + 128u * 1024u)   // 64 KB (2*16*512 dwords)
#define WS_XZ    (2u * 1024u * 1024u)             // 64 MB
// total: 66 MB

// ---------------------------------------------------------------------------
// Pack W and U (f32 [256][1024]) into bf16 B-fragment order:
// frag f = (ntile*8 + kstep)*64 + lane ; element j=0..7
// value = M[kstep*32 + (lane>>4)*8 + j][ntile*16 + (lane&15)]
// ---------------------------------------------------------------------------
__global__ void pack_weights(const float* __restrict__ W, const float* __restrict__ U,
                             bf16_t* __restrict__ Wp, bf16_t* __restrict__ Up) {
    int tid  = blockIdx.x * blockDim.x + threadIdx.x;   // 0..262143
    int j    = tid & 7;
    int lane = (tid >> 3) & 63;
    int ks   = (tid >> 9) & 7;
    int nt   = tid >> 12;
    int row  = ks * 32 + ((lane >> 4) << 3) + j;
    int col  = nt * 16 + (lane & 15);
    Wp[tid] = (bf16_t)W[row * G4 + col];
    Up[tid] = (bf16_t)U[row * G4 + col];
}

// ---------------------------------------------------------------------------
// Phase A: xz = emb[x] @ W + bias, stored bf16 in C-fragment order:
//   xz2[((t*4 + bchunk)*64 + ntile)*64 + lane] = bf16x4 {r=0..3}
// value[r] = z[batch = bchunk*16 + (lane>>4)*4 + r][col = ntile*16 + (lane&15)]
// ---------------------------------------------------------------------------
__global__ __launch_bounds__(256) void xz_gemm(const int* __restrict__ x,
                                               const float* __restrict__ emb,
                                               const bf16_t* __restrict__ Wp,
                                               const float* __restrict__ bias,
                                               bf16x4* __restrict__ xz2) {
    int nb   = blockIdx.x & 7;
    int t    = blockIdx.x >> 3;
    int w    = threadIdx.x >> 6;
    int lane = threadIdx.x & 63;
    int l15  = lane & 15;
    int quad = lane >> 4;

    int b_row = w * 16 + l15;
    int tok   = x[b_row * T_SZ + t];
    const float* erow = emb + (size_t)tok * 256;

    bf16x8 afrag[8];
#pragma unroll
    for (int ks = 0; ks < 8; ks++) {
        const float4* p = (const float4*)(erow + ks * 32 + quad * 8);
        float4 v0 = p[0], v1 = p[1];
        bf16x8 a;
        a[0] = (bf16_t)v0.x; a[1] = (bf16_t)v0.y; a[2] = (bf16_t)v0.z; a[3] = (bf16_t)v0.w;
        a[4] = (bf16_t)v1.x; a[5] = (bf16_t)v1.y; a[6] = (bf16_t)v1.z; a[7] = (bf16_t)v1.w;
        afrag[ks] = a;
    }

    const bf16x8* Wf = (const bf16x8*)Wp;

#pragma unroll
    for (int nt = 0; nt < 8; nt++) {
        int ntg = nb * 8 + nt;
        float bv = bias[ntg * 16 + l15];
        f32x4 acc = {bv, bv, bv, bv};
        const bf16x8* bp = Wf + (size_t)(ntg * 8) * 64 + lane;
#pragma unroll
        for (int ks = 0; ks < 8; ks++) {
            bf16x8 bfrag = bp[ks * 64];
            acc = __builtin_amdgcn_mfma_f32_16x16x32_bf16(afrag[ks], bfrag, acc, 0, 0, 0);
        }
        bf16x4 hv;
#pragma unroll
        for (int r = 0; r < 4; r++) hv[r] = (bf16_t)acc[r];
        xz2[((size_t)(t * 4 + w) * 64 + ntg) * 64 + lane] = hv;
    }
}

__device__ __forceinline__ float sigmoid_f(float z) {
    return 1.0f / (1.0f + __expf(-z));
}
__device__ __forceinline__ float tanh_f(float z) {
    float e = __expf(2.0f * z);
    return 1.0f - 2.0f / (e + 1.0f);
}
__device__ __forceinline__ unsigned pack2(float a, float b) {
    unsigned short xs = __builtin_bit_cast(unsigned short, (bf16_t)a);
    unsigned short ys = __builtin_bit_cast(unsigned short, (bf16_t)b);
    return (unsigned)xs | ((unsigned)ys << 16);
}
__device__ __forceinline__ bf16_t unpk_lo(unsigned v) {
    return __builtin_bit_cast(bf16_t, (unsigned short)(v & 0xffffu));
}
__device__ __forceinline__ bf16_t unpk_hi(unsigned v) {
    return __builtin_bit_cast(bf16_t, (unsigned short)(v >> 16));
}

__global__ void init_flags(unsigned* __restrict__ flag) {
    int i = blockIdx.x * 256 + threadIdx.x;
    if (i < T_SZ * 16) flag[i] = 0u;
}

// ---------------------------------------------------------------------------
// Phase B: recurrence. Grid: 16 blocks x 256 thr (4 waves).
// block = g*4 + u. Wave w owns unit-tile ut = u*4+w (units ut*16..+16) and
// computes ALL 4 gate z-tiles for it: ureg[G][ks], G=0..3 gates, pinned in
// VGPRs. Per step/wave: 4 independent chains of 8 MFMAs, gates+c+h fully
// in-lane, publish own 16 units to hexch + release flag; waves 1..3 spin on
// one sibling's flag each and pull its 64 units into h_lds.
// ---------------------------------------------------------------------------
__global__ __launch_bounds__(256, 1) void lstm_seq4w(const bf16x4* __restrict__ xz2,
                                                     const bf16_t* __restrict__ Up,
                                                     unsigned* __restrict__ flag,
                                                     unsigned* __restrict__ hexch,
                                                     float* __restrict__ hfin) {
    __shared__ __align__(16) bf16_t h_lds[16][264];   // [batch][unit(+pad)]

    const int u    = blockIdx.x & 3;
    const int g    = blockIdx.x >> 2;
    const int w    = threadIdx.x >> 6;    // 0..3: unit-tile within slice
    const int lane = threadIdx.x & 63;
    const int l15  = lane & 15;
    const int quad = lane >> 4;
    const int ut   = u * 4 + w;           // global 16-unit tile 0..15

    for (int i = threadIdx.x; i < 16 * 264; i += 256)
        (&h_lds[0][0])[i] = (bf16_t)0.0f;

    // load + PIN the U-slice: 4 gates x 8 k-steps = 128 VGPRs
    const bf16x8* Uf = (const bf16x8*)Up + lane;
    bf16x8 ureg[4][8];
#pragma unroll
    for (int G = 0; G < 4; G++) {
        int ntg = G * 16 + ut;
#pragma unroll
        for (int ks = 0; ks < 8; ks++)
            ureg[G][ks] = Uf[(ntg * 8 + ks) * 64];
    }
#pragma unroll
    for (int G = 0; G < 4; G++)
#pragma unroll
        for (int ks = 0; ks < 8; ks++) {
            f32x4 t4 = __builtin_bit_cast(f32x4, ureg[G][ks]);
            asm volatile("" : "+v"(t4));          // opaque: kills remat/sink
            ureg[G][ks] = __builtin_bit_cast(bf16x8, t4);
        }

    f32x4 cst = {0.f, 0.f, 0.f, 0.f};   // c state: batch quad*4+r, unit ut*16+l15

    bf16x8 af[8];                        // h_t A-frags; h0 = 0
#pragma unroll
    for (int ks = 0; ks < 8; ks++)
#pragma unroll
        for (int j = 0; j < 8; j++) af[ks][j] = (bf16_t)0.0f;

    bf16x4 xzv[4];
#pragma unroll
    for (int G = 0; G < 4; G++)
        xzv[G] = xz2[((size_t)(0 * 4 + g) * 64 + (G * 16 + ut)) * 64 + lane];

    __syncthreads();

    for (int t = 0; t < T_SZ; t++) {
        f32x4 acc[4];
#pragma unroll
        for (int G = 0; G < 4; G++) {
            f32x4 a = {(float)xzv[G][0], (float)xzv[G][1], (float)xzv[G][2], (float)xzv[G][3]};
            acc[G] = a;
        }
#pragma unroll
        for (int ks = 0; ks < 8; ks++)
#pragma unroll
            for (int G = 0; G < 4; G++)
                acc[G] = __builtin_amdgcn_mfma_f32_16x16x32_bf16(af[ks], ureg[G][ks], acc[G], 0, 0, 0);

        if (t + 1 < T_SZ) {   // prefetch next xz (lands during the spin)
#pragma unroll
            for (int G = 0; G < 4; G++)
                xzv[G] = xz2[((size_t)((t + 1) * 4 + g) * 64 + (G * 16 + ut)) * 64 + lane];
        }

        float hv[4];
#pragma unroll
        for (int r = 0; r < 4; r++) {
            float ig = sigmoid_f(acc[0][r]);
            float fg = sigmoid_f(acc[1][r]);
            float gg = tanh_f(acc[2][r]);
            float og = sigmoid_f(acc[3][r]);
            float cn = fg * cst[r] + ig * gg;
            cst[r] = cn;
            hv[r] = og * tanh_f(cn);
        }

        if (t == T_SZ - 1) {   // uniform exit across all blocks/waves
#pragma unroll
            for (int r = 0; r < 4; r++)
                hfin[(g * 16 + quad * 4 + r) * HID + ut * 16 + l15] = hv[r];
            break;
        }

        // own h -> LDS
#pragma unroll
        for (int r = 0; r < 4; r++)
            h_lds[quad * 4 + r][u * 64 + w * 16 + l15] = (bf16_t)hv[r];

        // publish own 16 units (release), then pull one sibling slice
        {
            unsigned dw0 = pack2(hv[0], hv[1]);
            unsigned dw1 = pack2(hv[2], hv[3]);
            unsigned sbase = (unsigned)(((t & 1) * 16 + blockIdx.x) * 512);
            unsigned di = (unsigned)(w * 16 + l15) * 8u + (unsigned)(quad * 2);
            __hip_atomic_store(&hexch[sbase + di],     dw0, __ATOMIC_RELAXED, __HIP_MEMORY_SCOPE_AGENT);
            __hip_atomic_store(&hexch[sbase + di + 1], dw1, __ATOMIC_RELAXED, __HIP_MEMORY_SCOPE_AGENT);
            __hip_atomic_store(&flag[t * 16 + blockIdx.x], 1u, __ATOMIC_RELEASE, __HIP_MEMORY_SCOPE_AGENT);
        }

        if (w > 0) {           // waves 1..3: sibling (u+w)&3
            int s = (u + w) & 3;
            const unsigned* fl = &flag[t * 16 + g * 4 + s];
            while (__hip_atomic_load(fl, __ATOMIC_ACQUIRE, __HIP_MEMORY_SCOPE_AGENT) == 0u) {}
            unsigned pbase = (unsigned)(((t & 1) * 16 + g * 4 + s) * 512) + (unsigned)lane * 8u;
            unsigned d[8];
#pragma unroll
            for (int j = 0; j < 8; j++)
                d[j] = __hip_atomic_load(&hexch[pbase + j], __ATOMIC_RELAXED, __HIP_MEMORY_SCOPE_AGENT);
#pragma unroll
            for (int j = 0; j < 8; j++) {
                h_lds[2 * j][s * 64 + lane]     = unpk_lo(d[j]);
                h_lds[2 * j + 1][s * 64 + lane] = unpk_hi(d[j]);
            }
        }
        __syncthreads();       // h_{t+1} complete in LDS

#pragma unroll
        for (int ks = 0; ks < 8; ks++)
            af[ks] = *(const bf16x8*)&h_lds[l15][ks * 32 + quad * 8];
        __syncthreads();       // protect reads from next iter's writes
    }
}

// ---------------------------------------------------------------------------
// Phase C: logits = h_T @ Wd + bd; softmax. One block per batch row.
// ---------------------------------------------------------------------------
__global__ void head(const float* __restrict__ hfin, const float* __restrict__ Wd,
                     const float* __restrict__ bd, float* __restrict__ out) {
    __shared__ float hrow[HID];
    __shared__ float lg[32];
    __shared__ float ex[32];
    int b = blockIdx.x, tid = threadIdx.x;   // 64 threads
    for (int i = tid; i < HID; i += 64) hrow[i] = hfin[b * HID + i];
    __syncthreads();
    if (tid < NCLS) {
        float acc = bd[tid];
        for (int k = 0; k < HID; k++) acc = fmaf(hrow[k], Wd[k * NCLS + tid], acc);
        lg[tid] = acc;
    }
    __syncthreads();
    if (tid < NCLS) {
        float m = -1e30f;
        for (int jj = 0; jj < NCLS; jj++) m = fmaxf(m, lg[jj]);
        ex[tid] = __expf(lg[tid] - m);
    }
    __syncthreads();
    if (tid < NCLS) {
        float sden = 0.0f;
        for (int jj = 0; jj < NCLS; jj++) sden += ex[jj];
        out[b * NCLS + tid] = ex[tid] / sden;
    }
}

// ---------------------------------------------------------------------------
extern "C" void kernel_launch(void* const* d_in, const int* in_sizes, int n_in,
                              void* d_out, int out_size, void* d_ws, size_t ws_size,
                              hipStream_t stream) {
    const int*   x    = (const int*)d_in[0];
    const float* emb  = (const float*)d_in[1];
    const float* W    = (const float*)d_in[2];
    const float* U    = (const float*)d_in[3];
    const float* bias = (const float*)d_in[4];
    const float* Wd   = (const float*)d_in[5];
    const float* bd   = (const float*)d_in[6];
    float* out = (float*)d_out;

    char* ws = (char*)d_ws;
    bf16_t*   Up    = (bf16_t*)(ws + WS_UPACK);
    bf16_t*   Wp    = (bf16_t*)(ws + WS_WPACK);
    float*    hf    = (float*)(ws + WS_HFIN);
    unsigned* flag  = (unsigned*)(ws + WS_FLAG);
    unsigned* hexch = (unsigned*)(ws + WS_HEXCH);
    bf16x4*   xz2   = (bf16x4*)(ws + WS_XZ);

    init_flags<<<dim3(32), dim3(256), 0, stream>>>(flag);
    pack_weights<<<dim3(1024), dim3(256), 0, stream>>>(W, U, Wp, Up);
    xz_gemm<<<dim3(4096), dim3(256), 0, stream>>>(x, emb, Wp, bias, xz2);
    lstm_seq4w<<<dim3(16), dim3(256), 0, stream>>>(xz2, Up, flag, hexch, hf);
    head<<<dim3(64), dim3(64), 0, stream>>>(hf, Wd, bd, out);
}